// Round 9
// baseline (121.257 us; speedup 1.0000x reference)
//
#include <hip/hip_runtime.h>
#include <cstdint>
#include <cstddef>

// Problem constants (fixed by the reference: N=4096, D=512)
constexpr int N_ROWS = 4096;
constexpr int D      = 512;
constexpr int M      = 8192;   // 2N
constexpr int NTILE  = 64;     // M / 128 : partials chunk grid
constexpr int NBLK   = NTILE * (NTILE + 1) / 2;   // 2080 upper-tri tile pairs
constexpr int NKT    = 8;      // K-iterations (64 k-bytes each)

using f32x16 = __attribute__((ext_vector_type(16))) float;
using i32x4  = __attribute__((ext_vector_type(4))) int;
using i32x8  = __attribute__((ext_vector_type(8))) int;

// sum of squares of the 4 fp8 e4m3 bytes in `pk` (selector must be literal)
#define SS_FP8(pk, accum)                                                           \
    do {                                                                            \
        float f0 = __builtin_amdgcn_cvt_f32_fp8((pk), 0);                           \
        float f1 = __builtin_amdgcn_cvt_f32_fp8((pk), 1);                           \
        float f2 = __builtin_amdgcn_cvt_f32_fp8((pk), 2);                           \
        float f3 = __builtin_amdgcn_cvt_f32_fp8((pk), 3);                           \
        (accum) += f0 * f0 + f1 * f1 + f2 * f2 + f3 * f3;                           \
    } while (0)

// ---------------------------------------------------------------------------
// zb BLOCKED-TILE layout (fp8 e4m3) for direct global->VGPR fragment loads
// with perfect coalescing (VERIFIED R7/R8, absmax 0.0):
//   tile(R, C) = rows [R*32, R*32+32) x k-bytes [C*64, C*64+64), 2048 B,
//   at offset (R*8 + C)*2048.  In-tile: off = (g&1)*1024 + (r*2+(g>>1))*16+b.
//   MFMA lane (l31, half): two dense-1KB loads at (2*l31+half)*16 (+0,+1024)
//   -> 32 contiguous k-bytes/lane == the verified MX fragment.
// ---------------------------------------------------------------------------

// ---------------------------------------------------------------------------
// Kernel 1: fused normalize + fp8-quantize + positive-pair logits (VERIFIED).
// ---------------------------------------------------------------------------
__global__ __launch_bounds__(256) void normpos_kernel(
    const float* __restrict__ emb_i, const float* __restrict__ emb_j,
    uint8_t* __restrict__ zb, float* __restrict__ diagss,
    float* __restrict__ pos)
{
    const int wave = threadIdx.x >> 6, lane = threadIdx.x & 63;
    const int k = blockIdx.x * 4 + wave;

    const float4* a = (const float4*)(emb_i + (size_t)k * D);
    const float4* b = (const float4*)(emb_j + (size_t)k * D);
    float4 a0 = a[lane * 2], a1 = a[lane * 2 + 1];
    float4 b0 = b[lane * 2], b1 = b[lane * 2 + 1];

    float ssi = a0.x*a0.x + a0.y*a0.y + a0.z*a0.z + a0.w*a0.w
              + a1.x*a1.x + a1.y*a1.y + a1.z*a1.z + a1.w*a1.w;
    float ssj = b0.x*b0.x + b0.y*b0.y + b0.z*b0.z + b0.w*b0.w
              + b1.x*b1.x + b1.y*b1.y + b1.z*b1.z + b1.w*b1.w;
    float dp  = a0.x*b0.x + a0.y*b0.y + a0.z*b0.z + a0.w*b0.w
              + a1.x*b1.x + a1.y*b1.y + a1.z*b1.z + a1.w*b1.w;
    #pragma unroll
    for (int off = 32; off; off >>= 1) {
        ssi += __shfl_xor(ssi, off, 64);
        ssj += __shfl_xor(ssj, off, 64);
        dp  += __shfl_xor(dp,  off, 64);
    }
    const float invi = rsqrtf(ssi), invj = rsqrtf(ssj);

    const float zi[8] = {a0.x*invi, a0.y*invi, a0.z*invi, a0.w*invi,
                         a1.x*invi, a1.y*invi, a1.z*invi, a1.w*invi};
    const float zj[8] = {b0.x*invj, b0.y*invj, b0.z*invj, b0.w*invj,
                         b1.x*invj, b1.y*invj, b1.z*invj, b1.w*invj};

    int pi0 = __builtin_amdgcn_cvt_pk_fp8_f32(zi[0], zi[1], 0, false);
    pi0     = __builtin_amdgcn_cvt_pk_fp8_f32(zi[2], zi[3], pi0, true);
    int pi1 = __builtin_amdgcn_cvt_pk_fp8_f32(zi[4], zi[5], 0, false);
    pi1     = __builtin_amdgcn_cvt_pk_fp8_f32(zi[6], zi[7], pi1, true);
    int pj0 = __builtin_amdgcn_cvt_pk_fp8_f32(zj[0], zj[1], 0, false);
    pj0     = __builtin_amdgcn_cvt_pk_fp8_f32(zj[2], zj[3], pj0, true);
    int pj1 = __builtin_amdgcn_cvt_pk_fp8_f32(zj[4], zj[5], 0, false);
    pj1     = __builtin_amdgcn_cvt_pk_fp8_f32(zj[6], zj[7], pj1, true);

    float dssi = 0.f, dssj = 0.f;
    SS_FP8(pi0, dssi);
    SS_FP8(pi1, dssi);
    SS_FP8(pj0, dssj);
    SS_FP8(pj1, dssj);

    // blocked-tile store (see layout comment above)
    const size_t off8 = (size_t)((k >> 5) * 8 + (lane >> 3)) * 2048
                      + (size_t)(((lane >> 1) & 1)) * 1024
                      + (size_t)(((k & 31) * 2 + ((lane >> 2) & 1))) * 16
                      + (size_t)((lane & 1)) * 8;
    const unsigned long long vi =
        ((unsigned long long)(unsigned)pi1 << 32) | (unsigned)pi0;
    const unsigned long long vj =
        ((unsigned long long)(unsigned)pj1 << 32) | (unsigned)pj0;
    *(unsigned long long*)(zb + off8)                       = vi;
    *(unsigned long long*)(zb + off8 + (size_t)N_ROWS * D)  = vj;

    #pragma unroll
    for (int off = 32; off; off >>= 1) {
        dssi += __shfl_xor(dssi, off, 64);
        dssj += __shfl_xor(dssj, off, 64);
    }
    if (lane == 0) {
        diagss[k]          = dssi;
        diagss[k + N_ROWS] = dssj;
        pos[k]             = 2.0f * dp * invi * invj;
    }
}

// ---------------------------------------------------------------------------
// Kernel 2: symmetric fused sim-GEMM, MX fp8 (e4m3, unit scales), no LDS
// staging, DEPTH-3 register pipeline.
//
// R8 post-mortem: the unroll-by-2 "pipeline" had prefetch DISTANCE of one
// MFMA-cluster (~70 cyc), not one iteration -- no cover against ~1-2.5k cyc
// L2/L3 latency. Also the acc[2][2] lives in 64 AGPRs NOT counted in
// VGPR_Count=68: unified usage ~132 > 128 caps residency at 2 blocks/CU
// (occupancy 25% across R7/R8), so TLP can't hide latency either.
// Fix: 4 named fragment sets, prefetch it+3 while computing it. Outstanding
// per wave = 24 KB (3 sets in flight); 8 waves/CU = 192 KB -> latency no
// longer binding; L1 return (~64 B/cyc) becomes the floor (~14 us).
// Registers: 4 sets x 32 VGPR + addr ~= 160 VGPR + 64 AGPR < 256 -> still
// 8 waves/CU (unchanged). Sets indexed it&3 inside a fully-unrolled
// constant-trip loop => all indices compile-time (rule #20).
// XCD-bijective swizzle kept (2080 = 8 x 260). Epilogue verified unchanged.
// ---------------------------------------------------------------------------
__global__ __launch_bounds__(256, 2) void simgemm_kernel(
    const uint8_t* __restrict__ zb, float* __restrict__ partials)
{
    __shared__ float rp[4][64];    // per-wave row partials
    __shared__ float cp4[4][64];   // per-wave col partials

    const int tid  = threadIdx.x;
    const int wave = tid >> 6, lane = tid & 63;
    const int l31  = lane & 31, half = lane >> 5;

    // XCD-bijective swizzle, then decode t -> (bi, bj), bi <= bj.
    const int t = ((int)(blockIdx.x & 7)) * (NBLK / 8) + ((int)blockIdx.x >> 3);
    int bi = (int)((129.0f - sqrtf(129.0f * 129.0f - 8.0f * (float)t)) * 0.5f);
    while (bi > 0 && bi * (129 - bi) / 2 > t) --bi;
    while ((bi + 1) * (129 - (bi + 1)) / 2 <= t) ++bi;
    const int bj = bi + (t - bi * (129 - bi) / 2);
    const bool diag = (bi == bj);

    const int wr = wave >> 1, wc = wave & 1;

    // Fragment base pointers (blocked-tile layout).
    const int lofs = ((l31 << 1) | half) * 16;
    const uint8_t* baseA0 = zb + (size_t)(bi * 4 + wr * 2    ) * 8 * 2048 + lofs;
    const uint8_t* baseA1 = zb + (size_t)(bi * 4 + wr * 2 + 1) * 8 * 2048 + lofs;
    const uint8_t* baseB0 = zb + (size_t)(bj * 4 + wc * 2    ) * 8 * 2048 + lofs;
    const uint8_t* baseB1 = zb + (size_t)(bj * 4 + wc * 2 + 1) * 8 * 2048 + lofs;

#define LDFRAG(DST, BP, IT)                                                         \
    do {                                                                            \
        i32x4 _lo = *(const i32x4*)((BP) + (size_t)(IT) * 2048);                    \
        i32x4 _hi = *(const i32x4*)((BP) + (size_t)(IT) * 2048 + 1024);             \
        DST = __builtin_shufflevector(_lo, _hi, 0, 1, 2, 3, 4, 5, 6, 7);            \
    } while (0)

#define LDSET(S, IT)                                                                \
    do {                                                                            \
        LDFRAG(fA0[S], baseA0, IT);                                                 \
        LDFRAG(fA1[S], baseA1, IT);                                                 \
        LDFRAG(fB0[S], baseB0, IT);                                                 \
        LDFRAG(fB1[S], baseB1, IT);                                                 \
    } while (0)

#define MFMA4(S)                                                                    \
    do {                                                                            \
        acc[0][0] = __builtin_amdgcn_mfma_scale_f32_32x32x64_f8f6f4(                \
            fA0[S], fB0[S], acc[0][0], 0, 0, 0, 0x7f7f7f7f, 0, 0x7f7f7f7f);         \
        acc[0][1] = __builtin_amdgcn_mfma_scale_f32_32x32x64_f8f6f4(                \
            fA0[S], fB1[S], acc[0][1], 0, 0, 0, 0x7f7f7f7f, 0, 0x7f7f7f7f);         \
        acc[1][0] = __builtin_amdgcn_mfma_scale_f32_32x32x64_f8f6f4(                \
            fA1[S], fB0[S], acc[1][0], 0, 0, 0, 0x7f7f7f7f, 0, 0x7f7f7f7f);         \
        acc[1][1] = __builtin_amdgcn_mfma_scale_f32_32x32x64_f8f6f4(                \
            fA1[S], fB1[S], acc[1][1], 0, 0, 0, 0x7f7f7f7f, 0, 0x7f7f7f7f);         \
    } while (0)

    f32x16 acc[2][2] = {};
    i32x8 fA0[4], fA1[4], fB0[4], fB1[4];   // 4 sets, static idx (unrolled)

    // Prologue: fill sets 0,1,2 (24 outstanding loads = 24 KB in flight).
    #pragma unroll
    for (int p = 0; p < 3; ++p)
        LDSET(p, p);

    // Main loop, fully unrolled (NKT=8): compute set it&3, prefetch it+3.
    #pragma unroll
    for (int it = 0; it < NKT; ++it) {
        if (it + 3 < NKT)
            LDSET((it + 3) & 3, it + 3);
        __builtin_amdgcn_sched_barrier(0);   // keep prefetch ABOVE the MFMAs
        MFMA4(it & 3);
    }

    // Epilogue (VERIFIED). C/D 32x32: col=l31, row=(reg&3)+8*(reg>>2)+4*half.
    // e = exp(sim/T) = exp(2*acc).
    float rowp[2][16] = {};
    #pragma unroll
    for (int j = 0; j < 2; ++j) {
        float cpj = 0.f;
        #pragma unroll
        for (int i = 0; i < 2; ++i)
            #pragma unroll
            for (int r = 0; r < 16; ++r) {
                float e = __expf(2.0f * acc[i][j][r]);
                rowp[i][r] += e;
                cpj += e;
            }
        if (!diag) {   // col partial over this wave's 64 rows
            cpj += __shfl_xor(cpj, 32, 64);
            if (half == 0) cp4[wave][j * 32 + l31] = cpj;
        }
    }
    #pragma unroll
    for (int i = 0; i < 2; ++i)
        #pragma unroll
        for (int r = 0; r < 16; ++r) {
            float e = rowp[i][r];
            e += __shfl_xor(e, 1, 64);
            e += __shfl_xor(e, 2, 64);
            e += __shfl_xor(e, 4, 64);
            e += __shfl_xor(e, 8, 64);
            e += __shfl_xor(e, 16, 64);
            if (l31 == 0)
                rp[wave][i * 32 + (r & 3) + 8 * (r >> 2) + 4 * half] = e;
        }
    __syncthreads();

    // rows 0-63 from waves {0,1}, 64-127 from {2,3};
    // cols 0-63 from waves {0,2}, 64-127 from {1,3}.
    float* pA = partials + (size_t)(bi * NTILE + bj) * 128;
    float* pB = partials + (size_t)(bj * NTILE + bi) * 128;
    if (tid < 128) {
        const int h = tid >> 6, rr = tid & 63;
        pA[tid] = rp[h * 2][rr] + rp[h * 2 + 1][rr];
    } else if (!diag) {
        const int c = tid - 128, h = c >> 6, cc = c & 63;
        pB[c] = cp4[h][cc] + cp4[h + 2][cc];
    }
}

// ---------------------------------------------------------------------------
// Kernel 3: per-tile-row reduction of partials + log terms + pos chunk.
// ---------------------------------------------------------------------------
__global__ __launch_bounds__(256) void rowfin_kernel(
    const float* __restrict__ partials, const float* __restrict__ diagss,
    const float* __restrict__ pos, float* __restrict__ lgpart)
{
    const int r  = blockIdx.x;          // tile-row 0..63
    const int ri = threadIdx.x & 127;   // row within tile
    const int ch = threadIdx.x >> 7;    // c-half 0/1
    const float* base = partials + (size_t)r * NTILE * 128 + ri;
    float s = 0.f;
    #pragma unroll
    for (int c = 0; c < 32; ++c)
        s += base[(size_t)(ch * 32 + c) * 128];
    __shared__ float half1[128];
    __shared__ float red[4];
    if (ch == 1) half1[ri] = s;
    __syncthreads();
    float lg = 0.f;
    if (ch == 0) {
        float rs = s + half1[ri];
        int row = r * 128 + ri;
        lg = __logf(rs - __expf(2.0f * diagss[row]));
    }
    if (threadIdx.x < 64)
        lg -= 2.0f * pos[r * 64 + threadIdx.x];
    #pragma unroll
    for (int off = 32; off; off >>= 1) lg += __shfl_xor(lg, off, 64);
    const int wave = threadIdx.x >> 6, lane = threadIdx.x & 63;
    if (lane == 0) red[wave] = lg;
    __syncthreads();
    if (threadIdx.x == 0) lgpart[r] = red[0] + red[1] + red[2] + red[3];
}

// ---------------------------------------------------------------------------
// Kernel 4: loss = sum_r lgpart[r] / 8192   (one wave)
// ---------------------------------------------------------------------------
__global__ __launch_bounds__(64) void loss_kernel(
    const float* __restrict__ lgpart, float* __restrict__ out)
{
    float local = lgpart[threadIdx.x];
    #pragma unroll
    for (int off = 32; off; off >>= 1) local += __shfl_xor(local, off, 64);
    if (threadIdx.x == 0) out[0] = local * (1.0f / 8192.0f);
}

// ---------------------------------------------------------------------------
extern "C" void kernel_launch(void* const* d_in, const int* in_sizes, int n_in,
                              void* d_out, int out_size, void* d_ws, size_t ws_size,
                              hipStream_t stream)
{
    const float* emb_i = (const float*)d_in[0];
    const float* emb_j = (const float*)d_in[1];

    // ws layout: zb fp8 [M][D] (4 MB, blocked-tile) | partials f32[64][64][128]
    //            (2 MB) | diagss f32[M] | pos f32[N] | lgpart f32[64]
    uint8_t* zb = (uint8_t*)d_ws;
    float* partials = (float*)((char*)d_ws + (size_t)M * D);
    float* diagss   = partials + (size_t)NTILE * NTILE * 128;
    float* pos      = diagss + M;
    float* lgpart   = pos + N_ROWS;
    float* out      = (float*)d_out;

    normpos_kernel<<<N_ROWS / 4, 256, 0, stream>>>(emb_i, emb_j, zb, diagss, pos);
    simgemm_kernel<<<NBLK, 256, 0, stream>>>(zb, partials);
    rowfin_kernel<<<NTILE, 256, 0, stream>>>(partials, diagss, pos, lgpart);
    loss_kernel<<<1, 64, 0, stream>>>(lgpart, out);
}